// Round 1
// baseline (80.789 us; speedup 1.0000x reference)
//
#include <hip/hip_runtime.h>
#include <stdint.h>

#define B_   4
#define N_   2048
#define C_   512
#define H_   4
#define HD_  128
#define BN_  (B_ * N_)
#define NIT_ 32
#define SCALE_ 0.08838834764831845f  // 1/sqrt(128)

typedef __attribute__((ext_vector_type(8))) short  short8;
typedef __attribute__((ext_vector_type(4))) unsigned short ushort4_t;
typedef __attribute__((ext_vector_type(4))) float  float4_t;
typedef __attribute__((ext_vector_type(8))) __bf16 bf16x8;

static __device__ __forceinline__ unsigned short f2bf(float f) {
  union { float f; uint32_t u; } v; v.f = f;
  uint32_t r = v.u + 0x7FFFu + ((v.u >> 16) & 1u);
  return (unsigned short)(r >> 16);
}

static __device__ __forceinline__ float4_t mfma16(short8 a, short8 b, float4_t c) {
  return __builtin_amdgcn_mfma_f32_16x16x32_bf16(
      __builtin_bit_cast(bf16x8, a), __builtin_bit_cast(bf16x8, b), c, 0, 0, 0);
}

#define GLOAD16(SRC, DST)                                               \
  __builtin_amdgcn_global_load_lds(                                     \
      (const __attribute__((address_space(1))) void*)(SRC),             \
      (__attribute__((address_space(3))) void*)(DST), 16, 0, 0)

// ---- kernel 1: per-token norm/var/sum + normalized bf16 x ------------------
__global__ __launch_bounds__(256) void k_stats(
    const float* __restrict__ x, unsigned short* __restrict__ xnq,
    float* __restrict__ diff, float* __restrict__ toksum) {
  int tok  = blockIdx.x * 4 + (threadIdx.x >> 6);
  int lane = threadIdx.x & 63;
  const float* xr = x + (size_t)tok * C_;
  float4_t a = *(const float4_t*)(xr + lane * 8);
  float4_t b = *(const float4_t*)(xr + lane * 8 + 4);
  float s = 0.f, ss = 0.f;
#pragma unroll
  for (int j = 0; j < 4; ++j) {
    s  += a[j] + b[j];
    ss += a[j] * a[j] + b[j] * b[j];
  }
#pragma unroll
  for (int o = 1; o < 64; o <<= 1) {
    s  += __shfl_xor(s, o);
    ss += __shfl_xor(ss, o);
  }
  float rn = 1.f / fmaxf(sqrtf(ss), 1e-12f);
  short8 o8;
#pragma unroll
  for (int j = 0; j < 4; ++j) {
    o8[j]     = (short)f2bf(a[j] * rn);
    o8[j + 4] = (short)f2bf(b[j] * rn);
  }
  *(short8*)(xnq + (size_t)tok * C_ + lane * 8) = o8;
  if (lane == 0) {
    diff[tok]   = (ss - s * s * (1.f / C_)) * (1.f / (C_ - 1));  // ddof=1
    toksum[tok] = s;
  }
}

// ---- kernel 1b: per-head transposed bf16 V: xvT[bh][d][n] ------------------
__global__ __launch_bounds__(256) void k_transpose(
    const float* __restrict__ x, unsigned short* __restrict__ xvT) {
  __shared__ float tr[HD_][65];
  int bh = blockIdx.x & 15, nt = blockIdx.x >> 4;
  int b = bh >> 2, h = bh & 3;
  int n0 = nt * 64, c0 = h * HD_;
  int t = threadIdx.x;
  int dm = (t & 31) * 4;
  int nr = t >> 5;
#pragma unroll
  for (int p = 0; p < 8; ++p) {
    int n = p * 8 + nr;
    float4_t v = *(const float4_t*)(x + ((size_t)(b * N_ + n0 + n)) * C_ + c0 + dm);
#pragma unroll
    for (int k = 0; k < 4; ++k) tr[dm + k][n] = v[k];
  }
  __syncthreads();
#pragma unroll
  for (int p = 0; p < 4; ++p) {
    int c = p * 256 + t;
    int d = c >> 3, nc = (c & 7) * 8;
    short8 o8;
#pragma unroll
    for (int e = 0; e < 8; ++e) o8[e] = (short)f2bf(tr[d][nc + e]);
    *(short8*)(xvT + ((size_t)bh * HD_ + d) * N_ + n0 + nc) = o8;
  }
}

// ---- kernel 2: global diff mean/std + per-batch gate -----------------------
__global__ __launch_bounds__(256) void k_finalize(
    const float* __restrict__ diff, const float* __restrict__ toksum,
    const float* __restrict__ gw, const float* __restrict__ gb,
    float* __restrict__ stats) {
  __shared__ float sh[4][8];
  int t = threadIdx.x, l = t & 63, w = t >> 6;
  float s1 = 0.f, s2 = 0.f;
  for (int i = t; i < BN_; i += 256) { float d = diff[i]; s1 += d; s2 += d * d; }
  float bs0 = 0.f, bs1 = 0.f, bs2 = 0.f, bs3 = 0.f;
  for (int i = t; i < N_; i += 256) {
    bs0 += toksum[i];          bs1 += toksum[N_ + i];
    bs2 += toksum[2 * N_ + i]; bs3 += toksum[3 * N_ + i];
  }
#pragma unroll
  for (int o = 1; o < 64; o <<= 1) {
    s1 += __shfl_xor(s1, o);  s2 += __shfl_xor(s2, o);
    bs0 += __shfl_xor(bs0, o); bs1 += __shfl_xor(bs1, o);
    bs2 += __shfl_xor(bs2, o); bs3 += __shfl_xor(bs3, o);
  }
  if (l == 0) {
    sh[w][0] = s1; sh[w][1] = s2;
    sh[w][2] = bs0; sh[w][3] = bs1; sh[w][4] = bs2; sh[w][5] = bs3;
  }
  __syncthreads();
  if (t == 0) {
    float S1 = sh[0][0] + sh[1][0] + sh[2][0] + sh[3][0];
    float S2 = sh[0][1] + sh[1][1] + sh[2][1] + sh[3][1];
    float mean = S1 / (float)BN_;
    float var  = (S2 - S1 * S1 / (float)BN_) / (float)(BN_ - 1);
    float rstd = 1.f / (sqrtf(var) + 1e-6f);
    stats[0] = mean; stats[1] = rstd;
    float w00 = gw[0], bb = gb[0];
#pragma unroll
    for (int q = 0; q < 4; ++q) {
      float bsum = sh[0][2 + q] + sh[1][2 + q] + sh[2][2 + q] + sh[3][2 + q];
      float gi = bsum / (float)(N_ * C_);
      stats[2 + q] = 1.f / (1.f + __expf(-(gi * w00 + bb)));
    }
  }
}

// ---- kernel 3: fused flash attention + edge/gate epilogue ------------------
// grid 512: block = (bh, qtile of 64 rows); 2 waves x 32 q-rows each.
// LDS: K tiles (64x128 bf16, 256B rows) and V^T tiles (128x64 bf16, 128B rows),
// both double-buffered = 64KB. Staged with global_load_lds w=16, source-side
// XOR swizzle; reads apply the matching XOR.
__global__ __launch_bounds__(128) void k_attn(
    const float* __restrict__ x, const unsigned short* __restrict__ xnq,
    const unsigned short* __restrict__ xvT, const float* __restrict__ diff,
    const float* __restrict__ stats, float* __restrict__ out) {
  __shared__ unsigned short sm[32768];
  int i  = blockIdx.x;
  int bh = ((i & 7) << 1) | ((i >> 3) & 1);   // XCD-affine: 2 heads per XCD
  int qt = i >> 4;
  int b = bh >> 2, h = bh & 3, c0 = h * HD_;
  int tid = threadIdx.x, w = tid >> 6, l = tid & 63;
  int g = l >> 4, r = l & 15;
  int q0 = qt * 64 + w * 32;

  // Q fragments (B-operand: col=query=r, k-slots = channels 8g+32cs+i)
  short8 qf[2][4];
  const unsigned short* qbase = xnq + ((size_t)(b * N_ + q0)) * C_ + c0;
#pragma unroll
  for (int sub = 0; sub < 2; ++sub)
#pragma unroll
    for (int cs = 0; cs < 4; ++cs)
      qf[sub][cs] = *(const short8*)(qbase + (size_t)(sub * 16 + r) * C_ + g * 8 + cs * 32);

  float4_t acc[2][8];
  float ls[2] = {0.f, 0.f};
#pragma unroll
  for (int sub = 0; sub < 2; ++sub)
#pragma unroll
    for (int dt = 0; dt < 8; ++dt)
      acc[sub][dt] = (float4_t){0.f, 0.f, 0.f, 0.f};

  auto stage = [&](int it, int cb) {
    // K tile: 16 instrs x 1KB (4 rows each); wave w does 8.
    const unsigned short* ks = xnq + ((size_t)(b * N_ + it * 64)) * C_ + c0;
    unsigned short* kd = &sm[cb * 8192];
#pragma unroll
    for (int jj = 0; jj < 8; ++jj) {
      int j = w * 8 + jj;
      int row = 4 * j + g;             // lane's dest row (dest = base + lane*16)
      int ssl = r ^ (row & 15);        // source slot: inverse of read XOR
      GLOAD16(ks + (size_t)row * C_ + ssl * 8, kd + j * 512);
    }
    // V^T tile: 16 instrs x 1KB (8 d-rows each)
    const unsigned short* vs = xvT + ((size_t)bh * HD_) * N_ + it * 64;
    unsigned short* vd = &sm[16384 + cb * 8192];
#pragma unroll
    for (int jj = 0; jj < 8; ++jj) {
      int j = w * 8 + jj;
      int d = 8 * j + (l >> 3);
      int ssl = (l & 7) ^ (d & 7);
      GLOAD16(vs + (size_t)d * N_ + ssl * 8, vd + j * 512);
    }
  };

  stage(0, 0);
  __syncthreads();

  for (int it = 0; it < NIT_; ++it) {
    int cb = it & 1;
    if (it + 1 < NIT_) stage(it + 1, cb ^ 1);
    const unsigned short* K = &sm[cb * 8192];
    const unsigned short* V = &sm[16384 + cb * 8192];

    // QK^T, swapped: S^T[key][query]; lane holds keys 16*t4+4g+j for query r
    float4_t p[2][4];
#pragma unroll
    for (int sub = 0; sub < 2; ++sub)
#pragma unroll
      for (int t4 = 0; t4 < 4; ++t4)
        p[sub][t4] = (float4_t){0.f, 0.f, 0.f, 0.f};

#pragma unroll
    for (int t4 = 0; t4 < 4; ++t4) {
#pragma unroll
      for (int cs = 0; cs < 4; ++cs) {
        short8 kf = *(const short8*)(K + (size_t)(t4 * 16 + r) * 128 +
                                     ((g * 8 + cs * 32) ^ (r * 8)));
        p[0][t4] = mfma16(kf, qf[0][cs], p[0][t4]);
        p[1][t4] = mfma16(kf, qf[1][cs], p[1][t4]);
      }
    }

    // softmax-lite: |s*scale| <= 0.0884 -> no max subtraction needed
    short8 pf[2][2];
#pragma unroll
    for (int sub = 0; sub < 2; ++sub)
#pragma unroll
      for (int t4 = 0; t4 < 4; ++t4) {
        float e0 = __expf(p[sub][t4][0] * SCALE_);
        float e1 = __expf(p[sub][t4][1] * SCALE_);
        float e2 = __expf(p[sub][t4][2] * SCALE_);
        float e3 = __expf(p[sub][t4][3] * SCALE_);
        ls[sub] += (e0 + e1) + (e2 + e3);
        pf[sub][t4 >> 1][(t4 & 1) * 4 + 0] = (short)f2bf(e0);
        pf[sub][t4 >> 1][(t4 & 1) * 4 + 1] = (short)f2bf(e1);
        pf[sub][t4 >> 1][(t4 & 1) * 4 + 2] = (short)f2bf(e2);
        pf[sub][t4 >> 1][(t4 & 1) * 4 + 3] = (short)f2bf(e3);
      }

    // PV: O^T = V^T * P^T; A k-slots = keys 4g+(i&3)+16*(i>>2)+32kt
    int sw = (r & 7) * 8;
#pragma unroll
    for (int dt = 0; dt < 8; ++dt) {
      const unsigned short* vrow = V + (size_t)(dt * 16 + r) * 64;
      union { short8 s8; ushort4_t h[2]; } vf0, vf1;
      vf0.h[0] = *(const ushort4_t*)(vrow + ((g * 4)      ^ sw));
      vf0.h[1] = *(const ushort4_t*)(vrow + ((g * 4 + 16) ^ sw));
      vf1.h[0] = *(const ushort4_t*)(vrow + ((g * 4 + 32) ^ sw));
      vf1.h[1] = *(const ushort4_t*)(vrow + ((g * 4 + 48) ^ sw));
      acc[0][dt] = mfma16(vf0.s8, pf[0][0], acc[0][dt]);
      acc[0][dt] = mfma16(vf1.s8, pf[0][1], acc[0][dt]);
      acc[1][dt] = mfma16(vf0.s8, pf[1][0], acc[1][dt]);
      acc[1][dt] = mfma16(vf1.s8, pf[1][1], acc[1][dt]);
    }
    __syncthreads();
  }

  // epilogue: finish ls reduction, fuse edge mask + gate + residual
#pragma unroll
  for (int sub = 0; sub < 2; ++sub) {
    ls[sub] += __shfl_xor(ls[sub], 16);
    ls[sub] += __shfl_xor(ls[sub], 32);
  }
  float mean = stats[0], rstd = stats[1], gate = stats[2 + b];
#pragma unroll
  for (int sub = 0; sub < 2; ++sub) {
    int q = q0 + sub * 16 + r;
    float dv = diff[b * N_ + q];
    float em = 1.f / (1.f + __expf(-(dv - mean) * rstd));
    float f  = gate * (1.f + 0.5f * em) / ls[sub];
    const float* xr = x + ((size_t)(b * N_ + q)) * C_;
    float* orow = out + ((size_t)(b * N_ + q)) * C_;
#pragma unroll
    for (int dt = 0; dt < 8; ++dt) {
      int dcol = c0 + dt * 16 + g * 4;   // C/D: row = 4g+j, col = r
      float4_t xin = *(const float4_t*)(xr + dcol);
      float4_t o;
#pragma unroll
      for (int j = 0; j < 4; ++j) o[j] = xin[j] + f * acc[sub][dt][j];
      *(float4_t*)(orow + dcol) = o;
    }
  }
}

extern "C" void kernel_launch(void* const* d_in, const int* in_sizes, int n_in,
                              void* d_out, int out_size, void* d_ws, size_t ws_size,
                              hipStream_t stream) {
  (void)in_sizes; (void)n_in; (void)out_size; (void)ws_size;
  const float* x  = (const float*)d_in[0];
  const float* gw = (const float*)d_in[1];
  const float* gb = (const float*)d_in[2];
  float* out = (float*)d_out;
  // ws layout: xnq bf16 [8192][512] | xvT bf16 [16][128][2048] | diff | toksum | stats
  unsigned short* xnq = (unsigned short*)d_ws;
  unsigned short* xvT = xnq + (size_t)BN_ * C_;
  float* diff   = (float*)(xvT + (size_t)BN_ * C_);
  float* toksum = diff + BN_;
  float* stats  = toksum + BN_;
  hipLaunchKernelGGL(k_stats, dim3(BN_ / 4), dim3(256), 0, stream, x, xnq, diff, toksum);
  hipLaunchKernelGGL(k_transpose, dim3(512), dim3(256), 0, stream, x, xvT);
  hipLaunchKernelGGL(k_finalize, dim3(1), dim3(256), 0, stream, diff, toksum, gw, gb, stats);
  hipLaunchKernelGGL(k_attn, dim3(512), dim3(128), 0, stream, x, xnq, xvT, diff, stats, out);
}

// Round 2
// 77.431 us; speedup vs baseline: 1.0434x; 1.0434x over previous
//
#include <hip/hip_runtime.h>
#include <stdint.h>

#define B_   4
#define N_   2048
#define C_   512
#define H_   4
#define HD_  128
#define BN_  (B_ * N_)
#define NIT_ 32
// exp(s/sqrt(128)) == exp2(s * SCALE_LOG2E)
#define SCALE_LOG2E 0.1275129727595311f

typedef __attribute__((ext_vector_type(8))) short  short8;
typedef __attribute__((ext_vector_type(4))) unsigned short ushort4_t;
typedef __attribute__((ext_vector_type(4))) float  float4_t;
typedef __attribute__((ext_vector_type(8))) __bf16 bf16x8;

static __device__ __forceinline__ unsigned short f2bf(float f) {
  union { float f; uint32_t u; } v; v.f = f;
  uint32_t r = v.u + 0x7FFFu + ((v.u >> 16) & 1u);
  return (unsigned short)(r >> 16);
}

static __device__ __forceinline__ uint32_t cvtpk_bf16(float lo, float hi) {
  uint32_t r;
  asm("v_cvt_pk_bf16_f32 %0, %1, %2" : "=v"(r) : "v"(lo), "v"(hi));
  return r;
}

#if __has_builtin(__builtin_amdgcn_exp2f)
#define EXP2(x) __builtin_amdgcn_exp2f(x)
#else
#define EXP2(x) exp2f(x)
#endif

static __device__ __forceinline__ float4_t mfma16(short8 a, short8 b, float4_t c) {
  return __builtin_amdgcn_mfma_f32_16x16x32_bf16(
      __builtin_bit_cast(bf16x8, a), __builtin_bit_cast(bf16x8, b), c, 0, 0, 0);
}

#define GLOAD16(SRC, DST)                                               \
  __builtin_amdgcn_global_load_lds(                                     \
      (const __attribute__((address_space(1))) void*)(SRC),             \
      (__attribute__((address_space(3))) void*)(DST), 16, 0, 0)

// ---- kernel 1: per-token norm/var/sum + normalized bf16 x ------------------
__global__ __launch_bounds__(256) void k_stats(
    const float* __restrict__ x, unsigned short* __restrict__ xnq,
    float* __restrict__ diff, float* __restrict__ toksum) {
  int tok  = blockIdx.x * 4 + (threadIdx.x >> 6);
  int lane = threadIdx.x & 63;
  const float* xr = x + (size_t)tok * C_;
  float4_t a = *(const float4_t*)(xr + lane * 8);
  float4_t b = *(const float4_t*)(xr + lane * 8 + 4);
  float s = 0.f, ss = 0.f;
#pragma unroll
  for (int j = 0; j < 4; ++j) {
    s  += a[j] + b[j];
    ss += a[j] * a[j] + b[j] * b[j];
  }
#pragma unroll
  for (int o = 1; o < 64; o <<= 1) {
    s  += __shfl_xor(s, o);
    ss += __shfl_xor(ss, o);
  }
  float rn = 1.f / fmaxf(sqrtf(ss), 1e-12f);
  short8 o8;
#pragma unroll
  for (int j = 0; j < 4; ++j) {
    o8[j]     = (short)f2bf(a[j] * rn);
    o8[j + 4] = (short)f2bf(b[j] * rn);
  }
  *(short8*)(xnq + (size_t)tok * C_ + lane * 8) = o8;
  if (lane == 0) {
    diff[tok]   = (ss - s * s * (1.f / C_)) * (1.f / (C_ - 1));  // ddof=1
    toksum[tok] = s;
  }
}

// ---- kernel 1b: per-head transposed bf16 V with baked LDS swizzle ---------
// xvT[bh][d][seg of 64 n]: within each 64-ushort segment, the 16 8-byte
// halves are stored permuted: position p holds logical half p ^ P(d),
// P(d) = ((d&7)<<1) | ((d>>3)&1).  Staging into LDS is then purely linear
// and the LDS read XOR ((r&7)<<3)|(r3<<2) is bank-conflict-free.
__global__ __launch_bounds__(256) void k_transpose(
    const float* __restrict__ x, unsigned short* __restrict__ xvT) {
  __shared__ float tr[HD_][65];
  int bh = blockIdx.x & 15, nt = blockIdx.x >> 4;
  int b = bh >> 2, h = bh & 3;
  int n0 = nt * 64, c0 = h * HD_;
  int t = threadIdx.x;
  int dm = (t & 31) * 4;
  int nr = t >> 5;
#pragma unroll
  for (int p = 0; p < 8; ++p) {
    int n = p * 8 + nr;
    float4_t v = *(const float4_t*)(x + ((size_t)(b * N_ + n0 + n)) * C_ + c0 + dm);
#pragma unroll
    for (int k = 0; k < 4; ++k) tr[dm + k][n] = v[k];
  }
  __syncthreads();
#pragma unroll
  for (int p = 0; p < 4; ++p) {
    int c = p * 256 + t;
    int d = c >> 3, nc = (c & 7) * 8;       // 8 ushorts = halves q0, q0+1
    int P = ((d & 7) << 1) | ((d >> 3) & 1);
    int q0h = nc >> 2;
    ushort4_t h0, h1;
#pragma unroll
    for (int e = 0; e < 4; ++e) {
      h0[e] = f2bf(tr[d][nc + e]);
      h1[e] = f2bf(tr[d][nc + 4 + e]);
    }
    unsigned short* base = xvT + ((size_t)bh * HD_ + d) * N_ + n0;
    *(ushort4_t*)(base + (((q0h    ) ^ P) << 2)) = h0;
    *(ushort4_t*)(base + (((q0h + 1) ^ P) << 2)) = h1;
  }
}

// ---- kernel 2: global diff mean/std + per-batch gate -----------------------
__global__ __launch_bounds__(256) void k_finalize(
    const float* __restrict__ diff, const float* __restrict__ toksum,
    const float* __restrict__ gw, const float* __restrict__ gb,
    float* __restrict__ stats) {
  __shared__ float sh[4][8];
  int t = threadIdx.x, l = t & 63, w = t >> 6;
  float s1 = 0.f, s2 = 0.f;
  for (int i = t; i < BN_; i += 256) { float d = diff[i]; s1 += d; s2 += d * d; }
  float bs0 = 0.f, bs1 = 0.f, bs2 = 0.f, bs3 = 0.f;
  for (int i = t; i < N_; i += 256) {
    bs0 += toksum[i];          bs1 += toksum[N_ + i];
    bs2 += toksum[2 * N_ + i]; bs3 += toksum[3 * N_ + i];
  }
#pragma unroll
  for (int o = 1; o < 64; o <<= 1) {
    s1 += __shfl_xor(s1, o);  s2 += __shfl_xor(s2, o);
    bs0 += __shfl_xor(bs0, o); bs1 += __shfl_xor(bs1, o);
    bs2 += __shfl_xor(bs2, o); bs3 += __shfl_xor(bs3, o);
  }
  if (l == 0) {
    sh[w][0] = s1; sh[w][1] = s2;
    sh[w][2] = bs0; sh[w][3] = bs1; sh[w][4] = bs2; sh[w][5] = bs3;
  }
  __syncthreads();
  if (t == 0) {
    float S1 = sh[0][0] + sh[1][0] + sh[2][0] + sh[3][0];
    float S2 = sh[0][1] + sh[1][1] + sh[2][1] + sh[3][1];
    float mean = S1 / (float)BN_;
    float var  = (S2 - S1 * S1 / (float)BN_) / (float)(BN_ - 1);
    float rstd = 1.f / (sqrtf(var) + 1e-6f);
    stats[0] = mean; stats[1] = rstd;
    float w00 = gw[0], bb = gb[0];
#pragma unroll
    for (int q = 0; q < 4; ++q) {
      float bsum = sh[0][2 + q] + sh[1][2 + q] + sh[2][2 + q] + sh[3][2 + q];
      float gi = bsum / (float)(N_ * C_);
      stats[2 + q] = 1.f / (1.f + __expf(-(gi * w00 + bb)));
    }
  }
}

// ---- kernel 3: fused flash attention + edge/gate epilogue ------------------
// grid 512: block = (bh, qtile of 64 rows); 4 waves x 16 q-rows each.
// LDS 64KB: K tiles (64x128 bf16) + V^T tiles (128x64 bf16), double-buffered.
// -> 2 blocks/CU, 8 waves/CU (2/SIMD) for MFMA/VALU cross-wave overlap.
__global__ __launch_bounds__(256) void k_attn(
    const float* __restrict__ x, const unsigned short* __restrict__ xnq,
    const unsigned short* __restrict__ xvT, const float* __restrict__ diff,
    const float* __restrict__ stats, float* __restrict__ out) {
  __shared__ unsigned short sm[32768];
  int i  = blockIdx.x;
  int bh = ((i & 7) << 1) | ((i >> 3) & 1);   // XCD-affine: same bh stays on one XCD
  int qt = i >> 4;
  int b = bh >> 2, h = bh & 3, c0 = h * HD_;
  int tid = threadIdx.x, w = tid >> 6, l = tid & 63;
  int g = l >> 4, r = l & 15;
  int r3 = (r >> 3) & 1;
  int q0 = qt * 64 + w * 16;

  // Q fragments (B-operand: col=query=r, k-slots = channels 8g+32cs+i)
  short8 qf[4];
  const unsigned short* qbase = xnq + ((size_t)(b * N_ + q0)) * C_ + c0;
#pragma unroll
  for (int cs = 0; cs < 4; ++cs)
    qf[cs] = *(const short8*)(qbase + (size_t)r * C_ + g * 8 + cs * 32);

  float4_t acc[8];
  float ls = 0.f;
#pragma unroll
  for (int dt = 0; dt < 8; ++dt) acc[dt] = (float4_t){0.f, 0.f, 0.f, 0.f};

  auto stage = [&](int it, int cb) {
    // K tile: 16 instrs x 1KB (4 rows each); wave w does 4.
    const unsigned short* ks = xnq + ((size_t)(b * N_ + it * 64)) * C_ + c0;
    unsigned short* kd = &sm[cb * 8192];
#pragma unroll
    for (int jj = 0; jj < 4; ++jj) {
      int j = w * 4 + jj;
      int row = 4 * j + g;             // lane's dest row (dest = base + lane*16)
      int ssl = r ^ (row & 15);        // source slot: inverse of read XOR
      GLOAD16(ks + (size_t)row * C_ + ssl * 8, kd + j * 512);
    }
    // V^T tile: 16 instrs x 1KB (8 d-rows each); source already swizzled.
    const unsigned short* vs = xvT + ((size_t)bh * HD_) * N_ + it * 64;
    unsigned short* vd = &sm[16384 + cb * 8192];
#pragma unroll
    for (int jj = 0; jj < 4; ++jj) {
      int j = w * 4 + jj;
      int d = 8 * j + (l >> 3);
      GLOAD16(vs + (size_t)d * N_ + (l & 7) * 8, vd + j * 512);
    }
  };

  stage(0, 0);
  __syncthreads();

  for (int it = 0; it < NIT_; ++it) {
    int cb = it & 1;
    if (it + 1 < NIT_) stage(it + 1, cb ^ 1);
    const unsigned short* K = &sm[cb * 8192];
    const unsigned short* V = &sm[16384 + cb * 8192];

    // QK^T, swapped: S^T[key][query]; lane holds keys 16*t4+4g+j for query r
    float4_t p[4];
#pragma unroll
    for (int t4 = 0; t4 < 4; ++t4) p[t4] = (float4_t){0.f, 0.f, 0.f, 0.f};

    __builtin_amdgcn_s_setprio(1);
#pragma unroll
    for (int t4 = 0; t4 < 4; ++t4) {
#pragma unroll
      for (int cs = 0; cs < 4; ++cs) {
        short8 kf = *(const short8*)(K + (size_t)(t4 * 16 + r) * 128 +
                                     ((g * 8 + cs * 32) ^ (r * 8)));
        p[t4] = mfma16(kf, qf[cs], p[t4]);
      }
    }
    __builtin_amdgcn_s_setprio(0);

    // softmax-lite: |s*scale| <= 0.0884 -> no max subtraction needed
    union { short8 s8; uint32_t u[4]; } pf[2];
#pragma unroll
    for (int t4 = 0; t4 < 4; ++t4) {
      float e0 = EXP2(p[t4][0] * SCALE_LOG2E);
      float e1 = EXP2(p[t4][1] * SCALE_LOG2E);
      float e2 = EXP2(p[t4][2] * SCALE_LOG2E);
      float e3 = EXP2(p[t4][3] * SCALE_LOG2E);
      ls += (e0 + e1) + (e2 + e3);
      pf[t4 >> 1].u[(t4 & 1) * 2 + 0] = cvtpk_bf16(e0, e1);
      pf[t4 >> 1].u[(t4 & 1) * 2 + 1] = cvtpk_bf16(e2, e3);
    }

    // PV: O^T = V^T * P^T; A k-slots = keys 4g+(i&3)+16*(i>>2)+32kt
    int X = ((r & 7) << 3) | (r3 << 2);   // ushort-offset XOR matching P(d)
    __builtin_amdgcn_s_setprio(1);
#pragma unroll
    for (int dt = 0; dt < 8; ++dt) {
      const unsigned short* vrow = V + (size_t)(dt * 16 + r) * 64;
      union { short8 s8; ushort4_t h[2]; } vf0, vf1;
      vf0.h[0] = *(const ushort4_t*)(vrow + ((g * 4)      ^ X));
      vf0.h[1] = *(const ushort4_t*)(vrow + ((g * 4 + 16) ^ X));
      vf1.h[0] = *(const ushort4_t*)(vrow + ((g * 4 + 32) ^ X));
      vf1.h[1] = *(const ushort4_t*)(vrow + ((g * 4 + 48) ^ X));
      acc[dt] = mfma16(vf0.s8, pf[0].s8, acc[dt]);
      acc[dt] = mfma16(vf1.s8, pf[1].s8, acc[dt]);
    }
    __builtin_amdgcn_s_setprio(0);
    __syncthreads();
  }

  // epilogue: finish ls reduction, fuse edge mask + gate + residual
  ls += __shfl_xor(ls, 16);
  ls += __shfl_xor(ls, 32);
  float mean = stats[0], rstd = stats[1], gate = stats[2 + b];
  int q = q0 + r;
  float dv = diff[b * N_ + q];
  float em = 1.f / (1.f + __expf(-(dv - mean) * rstd));
  float f  = gate * (1.f + 0.5f * em) / ls;
  const float* xr = x + ((size_t)(b * N_ + q)) * C_;
  float* orow = out + ((size_t)(b * N_ + q)) * C_;
#pragma unroll
  for (int dt = 0; dt < 8; ++dt) {
    int dcol = c0 + dt * 16 + g * 4;   // C/D: row = 4g+j, col = r
    float4_t xin = *(const float4_t*)(xr + dcol);
    float4_t o;
#pragma unroll
    for (int j = 0; j < 4; ++j) o[j] = xin[j] + f * acc[dt][j];
    *(float4_t*)(orow + dcol) = o;
  }
}

extern "C" void kernel_launch(void* const* d_in, const int* in_sizes, int n_in,
                              void* d_out, int out_size, void* d_ws, size_t ws_size,
                              hipStream_t stream) {
  (void)in_sizes; (void)n_in; (void)out_size; (void)ws_size;
  const float* x  = (const float*)d_in[0];
  const float* gw = (const float*)d_in[1];
  const float* gb = (const float*)d_in[2];
  float* out = (float*)d_out;
  // ws layout: xnq bf16 [8192][512] | xvT bf16 [16][128][2048] | diff | toksum | stats
  unsigned short* xnq = (unsigned short*)d_ws;
  unsigned short* xvT = xnq + (size_t)BN_ * C_;
  float* diff   = (float*)(xvT + (size_t)BN_ * C_);
  float* toksum = diff + BN_;
  float* stats  = toksum + BN_;
  hipLaunchKernelGGL(k_stats, dim3(BN_ / 4), dim3(256), 0, stream, x, xnq, diff, toksum);
  hipLaunchKernelGGL(k_transpose, dim3(512), dim3(256), 0, stream, x, xvT);
  hipLaunchKernelGGL(k_finalize, dim3(1), dim3(256), 0, stream, diff, toksum, gw, gb, stats);
  hipLaunchKernelGGL(k_attn, dim3(512), dim3(256), 0, stream, x, xnq, xvT, diff, stats, out);
}

// Round 3
// 77.190 us; speedup vs baseline: 1.0466x; 1.0031x over previous
//
#include <hip/hip_runtime.h>
#include <stdint.h>

#define B_   4
#define N_   2048
#define C_   512
#define H_   4
#define HD_  128
#define BN_  (B_ * N_)
#define NIT_ 32
// exp(s/sqrt(128)) == exp2(s * SCALE_LOG2E)
#define SCALE_LOG2E 0.1275129727595311f

typedef __attribute__((ext_vector_type(8))) short  short8;
typedef __attribute__((ext_vector_type(4))) unsigned short ushort4_t;
typedef __attribute__((ext_vector_type(4))) float  float4_t;
typedef __attribute__((ext_vector_type(8))) __bf16 bf16x8;

static __device__ __forceinline__ unsigned short f2bf(float f) {
  union { float f; uint32_t u; } v; v.f = f;
  uint32_t r = v.u + 0x7FFFu + ((v.u >> 16) & 1u);
  return (unsigned short)(r >> 16);
}

static __device__ __forceinline__ uint32_t cvtpk_bf16(float lo, float hi) {
  uint32_t r;
  asm("v_cvt_pk_bf16_f32 %0, %1, %2" : "=v"(r) : "v"(lo), "v"(hi));
  return r;
}

#if __has_builtin(__builtin_amdgcn_exp2f)
#define EXP2(x) __builtin_amdgcn_exp2f(x)
#else
#define EXP2(x) exp2f(x)
#endif

static __device__ __forceinline__ float4_t mfma16(short8 a, short8 b, float4_t c) {
  return __builtin_amdgcn_mfma_f32_16x16x32_bf16(
      __builtin_bit_cast(bf16x8, a), __builtin_bit_cast(bf16x8, b), c, 0, 0, 0);
}

#define GLOAD16(SRC, DST)                                               \
  __builtin_amdgcn_global_load_lds(                                     \
      (const __attribute__((address_space(1))) void*)(SRC),             \
      (__attribute__((address_space(3))) void*)(DST), 16, 0, 0)

// ---- kernel 1: per-token norm/var/sum + normalized bf16 x ------------------
__global__ __launch_bounds__(256) void k_stats(
    const float* __restrict__ x, unsigned short* __restrict__ xnq,
    float* __restrict__ diff, float* __restrict__ toksum) {
  int tok  = blockIdx.x * 4 + (threadIdx.x >> 6);
  int lane = threadIdx.x & 63;
  const float* xr = x + (size_t)tok * C_;
  float4_t a = *(const float4_t*)(xr + lane * 8);
  float4_t b = *(const float4_t*)(xr + lane * 8 + 4);
  float s = 0.f, ss = 0.f;
#pragma unroll
  for (int j = 0; j < 4; ++j) {
    s  += a[j] + b[j];
    ss += a[j] * a[j] + b[j] * b[j];
  }
#pragma unroll
  for (int o = 1; o < 64; o <<= 1) {
    s  += __shfl_xor(s, o);
    ss += __shfl_xor(ss, o);
  }
  float rn = 1.f / fmaxf(sqrtf(ss), 1e-12f);
  short8 o8;
#pragma unroll
  for (int j = 0; j < 4; ++j) {
    o8[j]     = (short)f2bf(a[j] * rn);
    o8[j + 4] = (short)f2bf(b[j] * rn);
  }
  *(short8*)(xnq + (size_t)tok * C_ + lane * 8) = o8;
  if (lane == 0) {
    diff[tok]   = (ss - s * s * (1.f / C_)) * (1.f / (C_ - 1));  // ddof=1
    toksum[tok] = s;
  }
}

// ---- kernel 1b: per-head transposed bf16 V, MFMA-k-slot + bank layout -----
// xvT[bh][d] row of N ushorts, in 64-key segments of 8 phys 16B-blocks.
// Phys block p holds logical block l = p ^ (d&7); logical block l holds keys
// 32*(l>>2) + 4*(l&3) + 16*(e>>2) + (e&3), e=0..7 (MFMA A k-slot order).
__global__ __launch_bounds__(256) void k_transpose(
    const float* __restrict__ x, unsigned short* __restrict__ xvT) {
  __shared__ float tr[HD_][65];
  int bh = blockIdx.x & 15, nt = blockIdx.x >> 4;
  int b = bh >> 2, h = bh & 3;
  int n0 = nt * 64, c0 = h * HD_;
  int t = threadIdx.x;
  int dm = (t & 31) * 4;
  int nr = t >> 5;
#pragma unroll
  for (int p = 0; p < 8; ++p) {
    int n = p * 8 + nr;
    float4_t v = *(const float4_t*)(x + ((size_t)(b * N_ + n0 + n)) * C_ + c0 + dm);
#pragma unroll
    for (int k = 0; k < 4; ++k) tr[dm + k][n] = v[k];
  }
  __syncthreads();
#pragma unroll
  for (int p4 = 0; p4 < 4; ++p4) {
    int c = p4 * 256 + t;
    int d = c >> 3, pb = c & 7;
    int lg = pb ^ (d & 7);
    int kbase = 32 * (lg >> 2) + 4 * (lg & 3);
    short8 o8;
#pragma unroll
    for (int e = 0; e < 8; ++e)
      o8[e] = (short)f2bf(tr[d][kbase + 16 * (e >> 2) + (e & 3)]);
    *(short8*)(xvT + ((size_t)(bh * HD_ + d)) * N_ + n0 + pb * 8) = o8;
  }
}

// ---- kernel 2: global diff mean/std + per-batch gate -----------------------
__global__ __launch_bounds__(256) void k_finalize(
    const float* __restrict__ diff, const float* __restrict__ toksum,
    const float* __restrict__ gw, const float* __restrict__ gb,
    float* __restrict__ stats) {
  __shared__ float sh[4][8];
  int t = threadIdx.x, l = t & 63, w = t >> 6;
  float s1 = 0.f, s2 = 0.f;
  for (int i = t; i < BN_; i += 256) { float d = diff[i]; s1 += d; s2 += d * d; }
  float bs0 = 0.f, bs1 = 0.f, bs2 = 0.f, bs3 = 0.f;
  for (int i = t; i < N_; i += 256) {
    bs0 += toksum[i];          bs1 += toksum[N_ + i];
    bs2 += toksum[2 * N_ + i]; bs3 += toksum[3 * N_ + i];
  }
#pragma unroll
  for (int o = 1; o < 64; o <<= 1) {
    s1 += __shfl_xor(s1, o);  s2 += __shfl_xor(s2, o);
    bs0 += __shfl_xor(bs0, o); bs1 += __shfl_xor(bs1, o);
    bs2 += __shfl_xor(bs2, o); bs3 += __shfl_xor(bs3, o);
  }
  if (l == 0) {
    sh[w][0] = s1; sh[w][1] = s2;
    sh[w][2] = bs0; sh[w][3] = bs1; sh[w][4] = bs2; sh[w][5] = bs3;
  }
  __syncthreads();
  if (t == 0) {
    float S1 = sh[0][0] + sh[1][0] + sh[2][0] + sh[3][0];
    float S2 = sh[0][1] + sh[1][1] + sh[2][1] + sh[3][1];
    float mean = S1 / (float)BN_;
    float var  = (S2 - S1 * S1 / (float)BN_) / (float)(BN_ - 1);
    float rstd = 1.f / (sqrtf(var) + 1e-6f);
    stats[0] = mean; stats[1] = rstd;
    float w00 = gw[0], bb = gb[0];
#pragma unroll
    for (int q = 0; q < 4; ++q) {
      float bsum = sh[0][2 + q] + sh[1][2 + q] + sh[2][2 + q] + sh[3][2 + q];
      float gi = bsum / (float)(N_ * C_);
      stats[2 + q] = 1.f / (1.f + __expf(-(gi * w00 + bb)));
    }
  }
}

// ---- kernel 3: fused flash attention + edge/gate epilogue ------------------
// grid 512 x 128 threads: block = (bh, 64-q tile); 2 waves, KEY-SPLIT:
// each wave covers all 64 q for its 32-key half per tile; cross-wave O/ls
// reduction once at the end.  K: global->VGPR direct (L2-resident), single-
// buffered prefetch.  V: LDS double-buffer (2x16KB), b128 swizzled reads.
__global__ __launch_bounds__(128, 1) void k_attn(
    const float* __restrict__ x, const unsigned short* __restrict__ xnq,
    const unsigned short* __restrict__ xvT, const float* __restrict__ diff,
    const float* __restrict__ stats, float* __restrict__ out) {
  __shared__ unsigned short sm[16384];   // 32KB: V dbuf; reused for reductions
  int i  = blockIdx.x;
  int bh = ((i & 7) << 1) | ((i >> 3) & 1);   // XCD-affine
  int qt = i >> 4;
  int b = bh >> 2, h = bh & 3, c0 = h * HD_;
  int tid = threadIdx.x, w = tid >> 6, l = tid & 63;
  int g = l >> 4, r = l & 15;
  int q0 = qt * 64;

  // Q fragments: 64 q rows (4 subtiles), B-operand
  short8 qf[4][4];
  const unsigned short* qbase = xnq + ((size_t)(b * N_ + q0)) * C_ + c0;
#pragma unroll
  for (int qs = 0; qs < 4; ++qs)
#pragma unroll
    for (int cs = 0; cs < 4; ++cs)
      qf[qs][cs] = *(const short8*)(qbase + (size_t)(qs * 16 + r) * C_ + g * 8 + cs * 32);

  // K fragments for this wave's 32-key half (single-buffered prefetch)
  short8 kf[2][4];
  auto loadK = [&](int it) {
    const unsigned short* kb =
        xnq + ((size_t)(b * N_ + it * 64 + w * 32 + r)) * C_ + c0 + g * 8;
#pragma unroll
    for (int ks = 0; ks < 2; ++ks)
#pragma unroll
      for (int cs = 0; cs < 4; ++cs)
        kf[ks][cs] = *(const short8*)(kb + ks * 16 * C_ + cs * 32);
  };

  auto stageV = [&](int it, int cb) {
    const unsigned short* vsrc =
        xvT + ((size_t)(bh * HD_ + w * 64 + (l >> 3))) * N_ + it * 64 + (l & 7) * 8;
    unsigned short* vdst = &sm[cb * 8192 + w * 4096];
#pragma unroll
    for (int j = 0; j < 8; ++j)
      GLOAD16(vsrc + (size_t)j * 8 * N_, vdst + j * 512);
  };

  float4_t acc[8][4];
  float ls[4] = {0.f, 0.f, 0.f, 0.f};
#pragma unroll
  for (int dt = 0; dt < 8; ++dt)
#pragma unroll
    for (int qs = 0; qs < 4; ++qs) acc[dt][qs] = (float4_t){0.f, 0.f, 0.f, 0.f};

  int vre = r * 64 + (((w * 4 + g) ^ (r & 7)) * 8);  // per-lane V read offset

  loadK(0);
  stageV(0, 0);
  __syncthreads();

#pragma unroll 2
  for (int it = 0; it < NIT_; ++it) {
    int cb = it & 1;
    if (it + 1 < NIT_) stageV(it + 1, cb ^ 1);

    // QK^T (swapped): S^T tiles [16k x 16q]; lane: keys 16ks+4g+j, query qs*16+r
    float4_t p[2][4];
#pragma unroll
    for (int ks = 0; ks < 2; ++ks)
#pragma unroll
      for (int qs = 0; qs < 4; ++qs) p[ks][qs] = (float4_t){0.f, 0.f, 0.f, 0.f};

    __builtin_amdgcn_s_setprio(1);
#pragma unroll
    for (int ks = 0; ks < 2; ++ks)
#pragma unroll
      for (int cs = 0; cs < 4; ++cs) {
        short8 kfr = kf[ks][cs];
#pragma unroll
        for (int qs = 0; qs < 4; ++qs)
          p[ks][qs] = mfma16(kfr, qf[qs][cs], p[ks][qs]);
      }
    __builtin_amdgcn_s_setprio(0);

    if (it + 1 < NIT_) loadK(it + 1);   // prefetch next K half-tile into regs

    // softmax-lite (|s*scale| <= 0.0884): exp2, sum, pack to bf16 k-slots
    union { short8 s8; uint32_t u[4]; } pfq[4];
#pragma unroll
    for (int ks = 0; ks < 2; ++ks)
#pragma unroll
      for (int qs = 0; qs < 4; ++qs) {
        float e0 = EXP2(p[ks][qs][0] * SCALE_LOG2E);
        float e1 = EXP2(p[ks][qs][1] * SCALE_LOG2E);
        float e2 = EXP2(p[ks][qs][2] * SCALE_LOG2E);
        float e3 = EXP2(p[ks][qs][3] * SCALE_LOG2E);
        ls[qs] += (e0 + e1) + (e2 + e3);
        pfq[qs].u[ks * 2 + 0] = cvtpk_bf16(e0, e1);
        pfq[qs].u[ks * 2 + 1] = cvtpk_bf16(e2, e3);
      }

    // PV: O^T += V^T(half) * P^T; one K=32 MFMA per (dt,qs)
    __builtin_amdgcn_s_setprio(1);
#pragma unroll
    for (int dt = 0; dt < 8; ++dt) {
      short8 vf = *(const short8*)(&sm[cb * 8192 + dt * 1024 + vre]);
#pragma unroll
      for (int qs = 0; qs < 4; ++qs)
        acc[dt][qs] = mfma16(vf, pfq[qs].s8, acc[dt][qs]);
    }
    __builtin_amdgcn_s_setprio(0);
    __syncthreads();
  }

  // ---- epilogue: ls cross-lane+cross-wave, O cross-wave, fuse edge/gate ----
#pragma unroll
  for (int qs = 0; qs < 4; ++qs) {
    ls[qs] += __shfl_xor(ls[qs], 16);
    ls[qs] += __shfl_xor(ls[qs], 32);
  }
  float* smf = (float*)sm;
  if (g == 0) {
#pragma unroll
    for (int qs = 0; qs < 4; ++qs) smf[w * 64 + qs * 16 + r] = ls[qs];
  }
  __syncthreads();
  float lst[4];
#pragma unroll
  for (int qs = 0; qs < 4; ++qs)
    lst[qs] = smf[qs * 16 + r] + smf[64 + qs * 16 + r];
  __syncthreads();

  float4_t* ex = (float4_t*)sm;   // 2048 slots of 16B = 32KB
  if (w == 0) {
#pragma unroll
    for (int k = 0; k < 4; ++k)
#pragma unroll
      for (int qs = 0; qs < 4; ++qs)
        ex[l * 16 + ((k * 4 + qs) ^ (l & 15))] = acc[4 + k][qs];
  } else {
#pragma unroll
    for (int k = 0; k < 4; ++k)
#pragma unroll
      for (int qs = 0; qs < 4; ++qs)
        ex[1024 + l * 16 + ((k * 4 + qs) ^ (l & 15))] = acc[k][qs];
  }
  __syncthreads();
  if (w == 0) {
#pragma unroll
    for (int k = 0; k < 4; ++k)
#pragma unroll
      for (int qs = 0; qs < 4; ++qs) {
        float4_t o = ex[1024 + l * 16 + ((k * 4 + qs) ^ (l & 15))];
#pragma unroll
        for (int j = 0; j < 4; ++j) acc[k][qs][j] += o[j];
      }
  } else {
#pragma unroll
    for (int k = 0; k < 4; ++k)
#pragma unroll
      for (int qs = 0; qs < 4; ++qs) {
        float4_t o = ex[l * 16 + ((k * 4 + qs) ^ (l & 15))];
#pragma unroll
        for (int j = 0; j < 4; ++j) acc[4 + k][qs][j] += o[j];
      }
  }

  float mean = stats[0], rstd = stats[1], gate = stats[2 + b];
#pragma unroll
  for (int qs = 0; qs < 4; ++qs) {
    int q = q0 + qs * 16 + r;
    float dv = diff[b * N_ + q];
    float em = 1.f / (1.f + __expf(-(dv - mean) * rstd));
    float f  = gate * (1.f + 0.5f * em) / lst[qs];
    const float* xr = x + ((size_t)(b * N_ + q)) * C_;
    float* orow = out + ((size_t)(b * N_ + q)) * C_;
    if (w == 0) {
#pragma unroll
      for (int k = 0; k < 4; ++k) {
        int dcol = c0 + k * 16 + g * 4;       // dt = k
        float4_t xin = *(const float4_t*)(xr + dcol);
        float4_t o;
#pragma unroll
        for (int j = 0; j < 4; ++j) o[j] = xin[j] + f * acc[k][qs][j];
        *(float4_t*)(orow + dcol) = o;
      }
    } else {
#pragma unroll
      for (int k = 0; k < 4; ++k) {
        int dcol = c0 + (4 + k) * 16 + g * 4; // dt = 4+k
        float4_t xin = *(const float4_t*)(xr + dcol);
        float4_t o;
#pragma unroll
        for (int j = 0; j < 4; ++j) o[j] = xin[j] + f * acc[4 + k][qs][j];
        *(float4_t*)(orow + dcol) = o;
      }
    }
  }
}

extern "C" void kernel_launch(void* const* d_in, const int* in_sizes, int n_in,
                              void* d_out, int out_size, void* d_ws, size_t ws_size,
                              hipStream_t stream) {
  (void)in_sizes; (void)n_in; (void)out_size; (void)ws_size;
  const float* x  = (const float*)d_in[0];
  const float* gw = (const float*)d_in[1];
  const float* gb = (const float*)d_in[2];
  float* out = (float*)d_out;
  // ws layout: xnq bf16 [8192][512] | xvT bf16 [16][128][2048] | diff | toksum | stats
  unsigned short* xnq = (unsigned short*)d_ws;
  unsigned short* xvT = xnq + (size_t)BN_ * C_;
  float* diff   = (float*)(xvT + (size_t)BN_ * C_);
  float* toksum = diff + BN_;
  float* stats  = toksum + BN_;
  hipLaunchKernelGGL(k_stats, dim3(BN_ / 4), dim3(256), 0, stream, x, xnq, diff, toksum);
  hipLaunchKernelGGL(k_transpose, dim3(512), dim3(256), 0, stream, x, xvT);
  hipLaunchKernelGGL(k_finalize, dim3(1), dim3(256), 0, stream, diff, toksum, gw, gb, stats);
  hipLaunchKernelGGL(k_attn, dim3(512), dim3(128), 0, stream, x, xnq, xvT, diff, stats, out);
}

// Round 4
// 67.100 us; speedup vs baseline: 1.2040x; 1.1504x over previous
//
#include <hip/hip_runtime.h>
#include <stdint.h>

#define B_   4
#define N_   2048
#define C_   512
#define H_   4
#define HD_  128
#define BN_  (B_ * N_)
#define NIT_ 32
// exp(s/sqrt(128)) == exp2(s * SCALE_LOG2E)
#define SCALE_LOG2E 0.1275129727595311f

typedef __attribute__((ext_vector_type(8))) short  short8;
typedef __attribute__((ext_vector_type(4))) unsigned short ushort4_t;
typedef __attribute__((ext_vector_type(4))) float  float4_t;
typedef __attribute__((ext_vector_type(8))) __bf16 bf16x8;

static __device__ __forceinline__ unsigned short f2bf(float f) {
  union { float f; uint32_t u; } v; v.f = f;
  uint32_t r = v.u + 0x7FFFu + ((v.u >> 16) & 1u);
  return (unsigned short)(r >> 16);
}

static __device__ __forceinline__ uint32_t cvtpk_bf16(float lo, float hi) {
  uint32_t r;
  asm("v_cvt_pk_bf16_f32 %0, %1, %2" : "=v"(r) : "v"(lo), "v"(hi));
  return r;
}

#if __has_builtin(__builtin_amdgcn_exp2f)
#define EXP2(x) __builtin_amdgcn_exp2f(x)
#else
#define EXP2(x) exp2f(x)
#endif

static __device__ __forceinline__ float4_t mfma16(short8 a, short8 b, float4_t c) {
  return __builtin_amdgcn_mfma_f32_16x16x32_bf16(
      __builtin_bit_cast(bf16x8, a), __builtin_bit_cast(bf16x8, b), c, 0, 0, 0);
}

#define GLOAD16(SRC, DST)                                               \
  __builtin_amdgcn_global_load_lds(                                     \
      (const __attribute__((address_space(1))) void*)(SRC),             \
      (__attribute__((address_space(3))) void*)(DST), 16, 0, 0)

// ---- kernel 1: per-token norm/var/sum + normalized bf16 x ------------------
__global__ __launch_bounds__(256) void k_stats(
    const float* __restrict__ x, unsigned short* __restrict__ xnq,
    float* __restrict__ diff, float* __restrict__ toksum) {
  int tok  = blockIdx.x * 4 + (threadIdx.x >> 6);
  int lane = threadIdx.x & 63;
  const float* xr = x + (size_t)tok * C_;
  float4_t a = *(const float4_t*)(xr + lane * 8);
  float4_t b = *(const float4_t*)(xr + lane * 8 + 4);
  float s = 0.f, ss = 0.f;
#pragma unroll
  for (int j = 0; j < 4; ++j) {
    s  += a[j] + b[j];
    ss += a[j] * a[j] + b[j] * b[j];
  }
#pragma unroll
  for (int o = 1; o < 64; o <<= 1) {
    s  += __shfl_xor(s, o);
    ss += __shfl_xor(ss, o);
  }
  float rn = 1.f / fmaxf(sqrtf(ss), 1e-12f);
  short8 o8;
#pragma unroll
  for (int j = 0; j < 4; ++j) {
    o8[j]     = (short)f2bf(a[j] * rn);
    o8[j + 4] = (short)f2bf(b[j] * rn);
  }
  *(short8*)(xnq + (size_t)tok * C_ + lane * 8) = o8;
  if (lane == 0) {
    diff[tok]   = (ss - s * s * (1.f / C_)) * (1.f / (C_ - 1));  // ddof=1
    toksum[tok] = s;
  }
}

// ---- kernel 1b: per-head transposed bf16 V, MFMA-k-slot + bank layout -----
// xvT[bh][d] row of N ushorts, in 64-key segments of 8 phys 16B-blocks.
// Phys block p holds logical block l = p ^ (d&7); logical block l holds keys
// 32*(l>>2) + 4*(l&3) + 16*(e>>2) + (e&3), e=0..7 (MFMA A k-slot order).
__global__ __launch_bounds__(256) void k_transpose(
    const float* __restrict__ x, unsigned short* __restrict__ xvT) {
  __shared__ float tr[HD_][65];
  int bh = blockIdx.x & 15, nt = blockIdx.x >> 4;
  int b = bh >> 2, h = bh & 3;
  int n0 = nt * 64, c0 = h * HD_;
  int t = threadIdx.x;
  int dm = (t & 31) * 4;
  int nr = t >> 5;
#pragma unroll
  for (int p = 0; p < 8; ++p) {
    int n = p * 8 + nr;
    float4_t v = *(const float4_t*)(x + ((size_t)(b * N_ + n0 + n)) * C_ + c0 + dm);
#pragma unroll
    for (int k = 0; k < 4; ++k) tr[dm + k][n] = v[k];
  }
  __syncthreads();
#pragma unroll
  for (int p4 = 0; p4 < 4; ++p4) {
    int c = p4 * 256 + t;
    int d = c >> 3, pb = c & 7;
    int lg = pb ^ (d & 7);
    int kbase = 32 * (lg >> 2) + 4 * (lg & 3);
    short8 o8;
#pragma unroll
    for (int e = 0; e < 8; ++e)
      o8[e] = (short)f2bf(tr[d][kbase + 16 * (e >> 2) + (e & 3)]);
    *(short8*)(xvT + ((size_t)(bh * HD_ + d)) * N_ + n0 + pb * 8) = o8;
  }
}

// ---- kernel 2: global diff mean/std + per-batch gate -----------------------
__global__ __launch_bounds__(256) void k_finalize(
    const float* __restrict__ diff, const float* __restrict__ toksum,
    const float* __restrict__ gw, const float* __restrict__ gb,
    float* __restrict__ stats) {
  __shared__ float sh[4][8];
  int t = threadIdx.x, l = t & 63, w = t >> 6;
  float s1 = 0.f, s2 = 0.f;
  for (int i = t; i < BN_; i += 256) { float d = diff[i]; s1 += d; s2 += d * d; }
  float bs0 = 0.f, bs1 = 0.f, bs2 = 0.f, bs3 = 0.f;
  for (int i = t; i < N_; i += 256) {
    bs0 += toksum[i];          bs1 += toksum[N_ + i];
    bs2 += toksum[2 * N_ + i]; bs3 += toksum[3 * N_ + i];
  }
#pragma unroll
  for (int o = 1; o < 64; o <<= 1) {
    s1 += __shfl_xor(s1, o);  s2 += __shfl_xor(s2, o);
    bs0 += __shfl_xor(bs0, o); bs1 += __shfl_xor(bs1, o);
    bs2 += __shfl_xor(bs2, o); bs3 += __shfl_xor(bs3, o);
  }
  if (l == 0) {
    sh[w][0] = s1; sh[w][1] = s2;
    sh[w][2] = bs0; sh[w][3] = bs1; sh[w][4] = bs2; sh[w][5] = bs3;
  }
  __syncthreads();
  if (t == 0) {
    float S1 = sh[0][0] + sh[1][0] + sh[2][0] + sh[3][0];
    float S2 = sh[0][1] + sh[1][1] + sh[2][1] + sh[3][1];
    float mean = S1 / (float)BN_;
    float var  = (S2 - S1 * S1 / (float)BN_) / (float)(BN_ - 1);
    float rstd = 1.f / (sqrtf(var) + 1e-6f);
    stats[0] = mean; stats[1] = rstd;
    float w00 = gw[0], bb = gb[0];
#pragma unroll
    for (int q = 0; q < 4; ++q) {
      float bsum = sh[0][2 + q] + sh[1][2 + q] + sh[2][2 + q] + sh[3][2 + q];
      float gi = bsum / (float)(N_ * C_);
      stats[2 + q] = 1.f / (1.f + __expf(-(gi * w00 + bb)));
    }
  }
}

// ---- kernel 3: fused flash attention + edge/gate epilogue ------------------
// grid 256 (1 block/CU) x 512 threads (8 waves = 2/SIMD).
// Block = (bh, 128-q tile). Wave w: q-quarter qh=w>>1 (32 q), key-half kh=w&1
// (32 keys/iter). K tile (64x128, swizzled) and V^T tile (128x64, baked
// layout) both LDS double-buffered (2x16KB each = 64KB). One barrier/iter.
// All in-loop LDS reads are base+immediate (addrs precomputed, unroll 2).
// Cross-kh O/ls reduction via LDS at the end.
__global__ __launch_bounds__(512, 1) void k_attn(
    const float* __restrict__ x, const unsigned short* __restrict__ xnq,
    const unsigned short* __restrict__ xvT, const float* __restrict__ diff,
    const float* __restrict__ stats, float* __restrict__ out) {
  __shared__ unsigned short sm[32768];   // 64KB: K dbuf [0,32KB), V dbuf [32,64KB)
  int i  = blockIdx.x;
  int bh = ((i & 7) << 1) | ((i >> 3) & 1);   // XCD-affine: 2 heads per XCD
  int qt = i >> 4;                            // 0..15
  int b = bh >> 2, h = bh & 3, c0 = h * HD_;
  int tid = threadIdx.x, w = tid >> 6, l = tid & 63;
  int kh = w & 1, qh = w >> 1;
  int g = l >> 4, r = l & 15;
  int q0 = qt * 128 + qh * 32;

  // Q fragments: 2 q-subtiles x 4 channel-slices (B-operand)
  short8 qf[2][4];
  const unsigned short* qbase = xnq + ((size_t)(b * N_ + q0)) * C_ + c0;
#pragma unroll
  for (int qs = 0; qs < 2; ++qs)
#pragma unroll
    for (int cs = 0; cs < 4; ++cs)
      qf[qs][cs] = *(const short8*)(qbase + (size_t)(qs * 16 + r) * C_ + g * 8 + cs * 32);

  // precomputed LDS byte addresses (in-loop reads become base+imm)
  const char* smb = (const char*)sm;
  int kaddr[4];
#pragma unroll
  for (int cs = 0; cs < 4; ++cs)
    kaddr[cs] = (kh * 32 + r) * 256 + (((g * 8 + cs * 32) ^ (r * 8)) * 2);
  int vaddr = 32768 + r * 128 + (((kh * 4 + g) ^ (r & 7)) * 16);

  float4_t acc[8][2];
  float ls[2] = {0.f, 0.f};
#pragma unroll
  for (int dt = 0; dt < 8; ++dt)
#pragma unroll
    for (int qs = 0; qs < 2; ++qs) acc[dt][qs] = (float4_t){0.f, 0.f, 0.f, 0.f};

  auto stage = [&](int it, int cb) {
    // K tile 64x128 (16KB): 16 instrs, 2 per wave; row 4j+g, swizzled source.
    const unsigned short* ks = xnq + ((size_t)(b * N_ + it * 64)) * C_ + c0;
    unsigned short* kd = &sm[cb * 8192];
#pragma unroll
    for (int jj = 0; jj < 2; ++jj) {
      int j = w * 2 + jj;
      int row = 4 * j + g;
      int ssl = r ^ (row & 15);
      GLOAD16(ks + (size_t)row * C_ + ssl * 8, kd + j * 512 + 0);
    }
    // V^T tile 128x64 (16KB): 16 instrs, 2 per wave; source already baked.
    const unsigned short* vs = xvT + ((size_t)bh * HD_) * N_ + it * 64;
    unsigned short* vd = &sm[16384 + cb * 8192];
#pragma unroll
    for (int jj = 0; jj < 2; ++jj) {
      int j = w * 2 + jj;
      int d = 8 * j + (l >> 3);
      GLOAD16(vs + (size_t)d * N_ + (l & 7) * 8, vd + j * 512);
    }
  };

  stage(0, 0);
  __syncthreads();

#pragma unroll 2
  for (int it = 0; it < NIT_; ++it) {
    int cb = it & 1;
    if (it + 1 < NIT_) stage(it + 1, cb ^ 1);

    // K fragments for this wave's key half: 8 x ds_read_b128, base+imm
    short8 kf[2][4];
#pragma unroll
    for (int ks2 = 0; ks2 < 2; ++ks2)
#pragma unroll
      for (int cs = 0; cs < 4; ++cs)
        kf[ks2][cs] = *(const short8*)(smb + kaddr[cs] + cb * 16384 + ks2 * 4096);

    // QK^T (swapped): S^T tiles [16k x 16q]
    float4_t p[2][2];
#pragma unroll
    for (int ks2 = 0; ks2 < 2; ++ks2)
#pragma unroll
      for (int qs = 0; qs < 2; ++qs) p[ks2][qs] = (float4_t){0.f, 0.f, 0.f, 0.f};

    __builtin_amdgcn_s_setprio(1);
#pragma unroll
    for (int ks2 = 0; ks2 < 2; ++ks2)
#pragma unroll
      for (int cs = 0; cs < 4; ++cs) {
        short8 kfr = kf[ks2][cs];
#pragma unroll
        for (int qs = 0; qs < 2; ++qs)
          p[ks2][qs] = mfma16(kfr, qf[qs][cs], p[ks2][qs]);
      }
    __builtin_amdgcn_s_setprio(0);

    // softmax-lite (|s*scale| <= 0.0884): exp2, sum, pack bf16 k-slots
    union { short8 s8; uint32_t u[4]; } pfq[2];
#pragma unroll
    for (int ks2 = 0; ks2 < 2; ++ks2)
#pragma unroll
      for (int qs = 0; qs < 2; ++qs) {
        float e0 = EXP2(p[ks2][qs][0] * SCALE_LOG2E);
        float e1 = EXP2(p[ks2][qs][1] * SCALE_LOG2E);
        float e2 = EXP2(p[ks2][qs][2] * SCALE_LOG2E);
        float e3 = EXP2(p[ks2][qs][3] * SCALE_LOG2E);
        ls[qs] += (e0 + e1) + (e2 + e3);
        pfq[qs].u[ks2 * 2 + 0] = cvtpk_bf16(e0, e1);
        pfq[qs].u[ks2 * 2 + 1] = cvtpk_bf16(e2, e3);
      }

    // PV: O^T += V^T(half) * P^T; V reads base+imm
    __builtin_amdgcn_s_setprio(1);
#pragma unroll
    for (int dt = 0; dt < 8; ++dt) {
      short8 vf = *(const short8*)(smb + vaddr + cb * 16384 + dt * 2048);
#pragma unroll
      for (int qs = 0; qs < 2; ++qs)
        acc[dt][qs] = mfma16(vf, pfq[qs].s8, acc[dt][qs]);
    }
    __builtin_amdgcn_s_setprio(0);
    __syncthreads();
  }

  // ---- epilogue: ls cross-lane + cross-kh; O cross-kh; fuse edge/gate ----
#pragma unroll
  for (int qs = 0; qs < 2; ++qs) {
    ls[qs] += __shfl_xor(ls[qs], 16);
    ls[qs] += __shfl_xor(ls[qs], 32);
  }
  float* smf = (float*)sm;
  if (g == 0) {
    smf[w * 16 + r]       = ls[0];
    smf[128 + w * 16 + r] = ls[1];
  }
  __syncthreads();
  float lst[2];
  lst[0] = smf[(qh * 2) * 16 + r]       + smf[(qh * 2 + 1) * 16 + r];
  lst[1] = smf[128 + (qh * 2) * 16 + r] + smf[128 + (qh * 2 + 1) * 16 + r];
  __syncthreads();

  float4_t* ex = (float4_t*)sm;   // 4096 float4 slots = 64KB
  if (kh == 1) {
#pragma unroll
    for (int dt = 0; dt < 8; ++dt)
#pragma unroll
      for (int qs = 0; qs < 2; ++qs)
        ex[(qh * 64 + l) * 16 + ((dt * 2 + qs) ^ (l & 15))] = acc[dt][qs];
  }
  __syncthreads();
  if (kh == 0) {
#pragma unroll
    for (int dt = 0; dt < 8; ++dt)
#pragma unroll
      for (int qs = 0; qs < 2; ++qs) {
        float4_t o = ex[(qh * 64 + l) * 16 + ((dt * 2 + qs) ^ (l & 15))];
#pragma unroll
        for (int j = 0; j < 4; ++j) acc[dt][qs][j] += o[j];
      }

    float mean = stats[0], rstd = stats[1], gate = stats[2 + b];
#pragma unroll
    for (int qs = 0; qs < 2; ++qs) {
      int q = q0 + qs * 16 + r;
      float dv = diff[b * N_ + q];
      float em = 1.f / (1.f + __expf(-(dv - mean) * rstd));
      float f  = gate * (1.f + 0.5f * em) / lst[qs];
      const float* xr = x + ((size_t)(b * N_ + q)) * C_;
      float* orow = out + ((size_t)(b * N_ + q)) * C_;
#pragma unroll
      for (int dt = 0; dt < 8; ++dt) {
        int dcol = c0 + dt * 16 + g * 4;   // C/D: row = 4g+j, col = r
        float4_t xin = *(const float4_t*)(xr + dcol);
        float4_t o;
#pragma unroll
        for (int j = 0; j < 4; ++j) o[j] = xin[j] + f * acc[dt][qs][j];
        *(float4_t*)(orow + dcol) = o;
      }
    }
  }
}

extern "C" void kernel_launch(void* const* d_in, const int* in_sizes, int n_in,
                              void* d_out, int out_size, void* d_ws, size_t ws_size,
                              hipStream_t stream) {
  (void)in_sizes; (void)n_in; (void)out_size; (void)ws_size;
  const float* x  = (const float*)d_in[0];
  const float* gw = (const float*)d_in[1];
  const float* gb = (const float*)d_in[2];
  float* out = (float*)d_out;
  // ws layout: xnq bf16 [8192][512] | xvT bf16 [16][128][2048] | diff | toksum | stats
  unsigned short* xnq = (unsigned short*)d_ws;
  unsigned short* xvT = xnq + (size_t)BN_ * C_;
  float* diff   = (float*)(xvT + (size_t)BN_ * C_);
  float* toksum = diff + BN_;
  float* stats  = toksum + BN_;
  hipLaunchKernelGGL(k_stats, dim3(BN_ / 4), dim3(256), 0, stream, x, xnq, diff, toksum);
  hipLaunchKernelGGL(k_transpose, dim3(512), dim3(256), 0, stream, x, xvT);
  hipLaunchKernelGGL(k_finalize, dim3(1), dim3(256), 0, stream, diff, toksum, gw, gb, stats);
  hipLaunchKernelGGL(k_attn, dim3(256), dim3(512), 0, stream, x, xnq, xvT, diff, stats, out);
}